// Round 1
// baseline (379.514 us; speedup 1.0000x reference)
//
#include <hip/hip_runtime.h>
#include <hip/hip_bf16.h>

#define B_ 32
#define S_ 1024
#define C_ 256
#define SP 1040   // 8 left halo + 1024 + 8 right halo rows per batch

typedef float f32x4 __attribute__((ext_vector_type(4)));
typedef __bf16 bf16x8 __attribute__((ext_vector_type(8)));

// ---------------------------------------------------------------------------
// Repack W[co][ci][k] fp32 -> wb[j][c32][g][co][8] bf16 so that MFMA A-frag
// loads (16 lanes = 16 consecutive co, each 16B) are fully coalesced.
// dst index bits: e=i&7, co=(i>>3)&255, g=(i>>11)&3, c32=(i>>13)&7, j=i>>16
// ---------------------------------------------------------------------------
__global__ __launch_bounds__(256) void wcvt_kernel(const float* __restrict__ w,
                                                   __hip_bfloat16* __restrict__ wb,
                                                   int k, int n) {
    int i = blockIdx.x * 256 + threadIdx.x;
    if (i >= n) return;
    int e   = i & 7;
    int co  = (i >> 3) & 255;
    int g   = (i >> 11) & 3;
    int c32 = (i >> 13) & 7;
    int j   = i >> 16;
    int ci  = c32 * 32 + g * 8 + e;
    wb[i] = __float2bfloat16(w[(co * 256 + ci) * k + j]);
}

// ---------------------------------------------------------------------------
// prep: one wave per (b,t) row of 256 channels.
//   GATE: score = sigmoid(0.5*(y0+y1) + 0.1*max(y0,y1)), x *= (1+score)
//   NORM: ChannelNorm (unbiased var, /255) + ReLU -> bf16 into haloed y buffer
//   !NORM: write gated fp32 row to d_out
// ---------------------------------------------------------------------------
template<bool GATE, bool NORM>
__global__ __launch_bounds__(256) void prep_kernel(const float* __restrict__ in,
                                                   const float* __restrict__ fc,
                                                   const float* __restrict__ cw,
                                                   const float* __restrict__ cb,
                                                   __hip_bfloat16* __restrict__ yout,
                                                   float* __restrict__ fout) {
    const int lane = threadIdx.x & 63;
    const int rid  = blockIdx.x * 4 + (threadIdx.x >> 6);

    int b, t;
    __hip_bfloat16* drow = nullptr;
    if constexpr (NORM) {
        b = rid / SP;
        const int r = rid - b * SP;
        t = r - 8;
        drow = yout + ((size_t)(b * SP + r)) * C_ + lane * 4;
        if (t < 0 || t >= S_) {            // zero halo row
            *(ushort4*)drow = make_ushort4(0, 0, 0, 0);
            return;
        }
    } else {
        b = rid >> 10;
        t = rid & 1023;
    }

    const float* row = in + ((size_t)(b * S_ + t)) * C_;
    f32x4 xv = *(const f32x4*)(row + lane * 4);

    if constexpr (GATE) {
        f32x4 f0 = *(const f32x4*)(fc + lane * 4);
        f32x4 f1 = *(const f32x4*)(fc + C_ + lane * 4);
        float p = xv.x * f0.x + xv.y * f0.y + xv.z * f0.z + xv.w * f0.w;
        float q = xv.x * f1.x + xv.y * f1.y + xv.z * f1.z + xv.w * f1.w;
#pragma unroll
        for (int m = 32; m >= 1; m >>= 1) {
            p += __shfl_xor(p, m, 64);
            q += __shfl_xor(q, m, 64);
        }
        float s = 0.5f * (p + q) + 0.1f * fmaxf(p, q);
        float score = 1.0f / (1.0f + expf(-s));
        float gmul = 1.0f + score;
        xv.x *= gmul; xv.y *= gmul; xv.z *= gmul; xv.w *= gmul;
    }

    if constexpr (NORM) {
        float s1 = xv.x + xv.y + xv.z + xv.w;
        float s2 = xv.x * xv.x + xv.y * xv.y + xv.z * xv.z + xv.w * xv.w;
#pragma unroll
        for (int m = 32; m >= 1; m >>= 1) {
            s1 += __shfl_xor(s1, m, 64);
            s2 += __shfl_xor(s2, m, 64);
        }
        float mean = s1 * (1.0f / 256.0f);
        float var  = fmaxf((s2 - 256.0f * mean * mean) * (1.0f / 255.0f), 0.0f);
        float inv  = rsqrtf(var + 1e-5f);
        f32x4 w4 = *(const f32x4*)(cw + lane * 4);
        f32x4 b4 = *(const f32x4*)(cb + lane * 4);
        float v0 = fmaxf(0.0f, (xv.x - mean) * inv * w4.x + b4.x);
        float v1 = fmaxf(0.0f, (xv.y - mean) * inv * w4.y + b4.y);
        float v2 = fmaxf(0.0f, (xv.z - mean) * inv * w4.z + b4.z);
        float v3 = fmaxf(0.0f, (xv.w - mean) * inv * w4.w + b4.w);
        union { ushort4 u; __hip_bfloat16 h[4]; } o;
        o.h[0] = __float2bfloat16(v0);
        o.h[1] = __float2bfloat16(v1);
        o.h[2] = __float2bfloat16(v2);
        o.h[3] = __float2bfloat16(v3);
        *(ushort4*)drow = o.u;
    } else {
        *(f32x4*)(fout + ((size_t)(b * S_ + t)) * C_ + lane * 4) = xv;
    }
}

// ---------------------------------------------------------------------------
// conv: block = 4 waves, tile 256co x 64t, one batch b, K = KS*256.
// y staged once in LDS [72][256] bf16 with 16B-slot XOR swizzle (slot ^= r&7).
// A-frags (weights) loaded straight from repacked global (L2-resident,
// perfectly coalesced). No barriers in the K loop.
// ---------------------------------------------------------------------------
template<int KS, int PAD, int LVALID>
__global__ __launch_bounds__(256) void conv_kernel(const __hip_bfloat16* __restrict__ y,
                                                   const __hip_bfloat16* __restrict__ wb,
                                                   float* __restrict__ h) {
    __shared__ alignas(16) __hip_bfloat16 ly[72 * 256];
    const int tid  = threadIdx.x;
    const int lane = tid & 63;
    const int wv   = tid >> 6;
    const int tt   = blockIdx.x & 15;
    const int b    = blockIdx.x >> 4;
    const int t0   = tt << 6;

    // stage 72 rows x 256 ci (rows t0-PAD .. t0-PAD+71 in padded coords)
    {
        const __hip_bfloat16* ybase = y + ((size_t)(b * SP + 8 + t0 - PAD)) * C_;
#pragma unroll
        for (int c = 0; c < 9; ++c) {
            int u = c * 256 + tid;       // 16B unit
            int r = u >> 5, s = u & 31;
            bf16x8 v = *(const bf16x8*)(ybase + r * C_ + ((s ^ (r & 7)) << 3));
            *(bf16x8*)(ly + u * 8) = v;
        }
    }
    __syncthreads();

    f32x4 acc[4][4];
#pragma unroll
    for (int i = 0; i < 4; ++i)
#pragma unroll
        for (int j2 = 0; j2 < 4; ++j2)
            acc[i][j2] = f32x4{0.f, 0.f, 0.f, 0.f};

    const int l15 = lane & 15;
    const int g   = lane >> 4;
    const int co_base = wv * 64;

    for (int j = 0; j < KS; ++j) {
#pragma unroll
        for (int c32 = 0; c32 < 8; ++c32) {
            const __hip_bfloat16* wstep = wb + ((size_t)((j * 8 + c32) * 4 + g)) * 2048;
            bf16x8 a_f[4];
#pragma unroll
            for (int mf = 0; mf < 4; ++mf)
                a_f[mf] = *(const bf16x8*)(wstep + (co_base + mf * 16 + l15) * 8);
            bf16x8 b_f[4];
#pragma unroll
            for (int nf = 0; nf < 4; ++nf) {
                int r = nf * 16 + l15 + j;
                int ci8 = c32 * 4 + g;
                b_f[nf] = *(const bf16x8*)(ly + r * 256 + ((ci8 ^ (r & 7)) << 3));
            }
#pragma unroll
            for (int mf = 0; mf < 4; ++mf)
#pragma unroll
                for (int nf = 0; nf < 4; ++nf)
                    acc[mf][nf] = __builtin_amdgcn_mfma_f32_16x16x32_bf16(
                        a_f[mf], b_f[nf], acc[mf][nf], 0, 0, 0);
        }
    }

    // epilogue: D[row=co][col=t]; row = 4*(lane>>4)+reg, col = lane&15
    float* hb = h + ((size_t)(b * S_ + t0)) * C_;
#pragma unroll
    for (int nf = 0; nf < 4; ++nf) {
        int tl = nf * 16 + l15;
#pragma unroll
        for (int mf = 0; mf < 4; ++mf) {
            int co = co_base + mf * 16 + g * 4;
            f32x4 v = acc[mf][nf];
            if (LVALID < S_ && (t0 + tl) >= LVALID)
                v = f32x4{0.f, 0.f, 0.f, 0.f};
            *(f32x4*)(hb + tl * 256 + co) = v;
        }
    }
}

// ---------------------------------------------------------------------------
extern "C" void kernel_launch(void* const* d_in, const int* in_sizes, int n_in,
                              void* d_out, int out_size, void* d_ws, size_t ws_size,
                              hipStream_t stream) {
    const float* inputs = (const float*)d_in[0];
    const float* cw[5] = { (const float*)d_in[1],  (const float*)d_in[4],
                           (const float*)d_in[7],  (const float*)d_in[10],
                           (const float*)d_in[13] };
    const float* cb[5] = { (const float*)d_in[2],  (const float*)d_in[5],
                           (const float*)d_in[8],  (const float*)d_in[11],
                           (const float*)d_in[14] };
    const float* Wf[5] = { (const float*)d_in[3],  (const float*)d_in[6],
                           (const float*)d_in[9],  (const float*)d_in[12],
                           (const float*)d_in[15] };
    const float* fc = (const float*)d_in[16];

    char* ws = (char*)d_ws;
    __hip_bfloat16* y = (__hip_bfloat16*)ws;              // 32*1040*256*2 = 17,039,360 B
    float* h = (float*)(ws + 17039360);                   // 32*1024*256*4 = 33,554,432 B
    __hip_bfloat16* wb[5];
    size_t off = 17039360 + 33554432;
    for (int l = 0; l < 5; ++l) {
        wb[l] = (__hip_bfloat16*)(ws + off);
        off += (size_t)(l + 4) * 65536 * 2;
    }
    float* out = (float*)d_out;

    for (int l = 0; l < 5; ++l) {
        int k = l + 4, n = k * 65536;
        wcvt_kernel<<<(n + 255) / 256, 256, 0, stream>>>(Wf[l], wb[l], k, n);
    }

    const int GN = (B_ * SP) / 4;   // 8320 blocks, 4 rows each
    prep_kernel<false, true><<<GN, 256, 0, stream>>>(inputs, fc, cw[0], cb[0], y, nullptr);
    conv_kernel<4, 1, 1023><<<512, 256, 0, stream>>>(y, wb[0], h);
    prep_kernel<true, true><<<GN, 256, 0, stream>>>(h, fc, cw[1], cb[1], y, nullptr);
    conv_kernel<5, 2, 1024><<<512, 256, 0, stream>>>(y, wb[1], h);
    prep_kernel<true, true><<<GN, 256, 0, stream>>>(h, fc, cw[2], cb[2], y, nullptr);
    conv_kernel<6, 2, 1023><<<512, 256, 0, stream>>>(y, wb[2], h);
    prep_kernel<true, true><<<GN, 256, 0, stream>>>(h, fc, cw[3], cb[3], y, nullptr);
    conv_kernel<7, 3, 1024><<<512, 256, 0, stream>>>(y, wb[3], h);
    prep_kernel<true, true><<<GN, 256, 0, stream>>>(h, fc, cw[4], cb[4], y, nullptr);
    conv_kernel<8, 3, 1023><<<512, 256, 0, stream>>>(y, wb[4], h);
    prep_kernel<true, false><<<(B_ * S_) / 4, 256, 0, stream>>>(h, fc, nullptr, nullptr, nullptr, out);
}

// Round 4
// 374.698 us; speedup vs baseline: 1.0129x; 1.0129x over previous
//
#include <hip/hip_runtime.h>
#include <hip/hip_bf16.h>

#define B_ 32
#define S_ 1024
#define C_ 256
#define SP 1040   // 8 left halo + 1024 + 8 right halo rows per batch

typedef float f32x4  __attribute__((ext_vector_type(4)));
typedef float f32x16 __attribute__((ext_vector_type(16)));
typedef __bf16 bf16x8 __attribute__((ext_vector_type(8)));
typedef __bf16 bf16x4 __attribute__((ext_vector_type(4)));

// ---------------------------------------------------------------------------
// Repack W[co][ci][k] fp32 -> bf16 for 32x32x16 MFMA A-frags.
// dst bits: e=i&7, co=(i>>3)&255, h=(i>>11)&1, ks=(i>>12)&1, c32=(i>>13)&7, j=i>>16
// ci = c32*32 + ks*16 + h*8 + e
// A-frag load (lane l, step s=j*8+c32): 16B at (s*4 + ks*2 + (l>>5))*2048 + co*8
// ---------------------------------------------------------------------------
__global__ __launch_bounds__(256) void wcvt_kernel(const float* __restrict__ w,
                                                   __hip_bfloat16* __restrict__ wb,
                                                   int k, int n) {
    int i = blockIdx.x * 256 + threadIdx.x;
    if (i >= n) return;
    int e   = i & 7;
    int co  = (i >> 3) & 255;
    int hh  = (i >> 11) & 1;
    int ks  = (i >> 12) & 1;
    int c32 = (i >> 13) & 7;
    int j   = i >> 16;
    int ci  = c32 * 32 + ks * 16 + hh * 8 + e;
    wb[i] = __float2bfloat16(w[(co * 256 + ci) * k + j]);
}

// ---------------------------------------------------------------------------
// prep: one wave per (b,t) row of 256 channels.
//   GATE: score = sigmoid(0.5*(y0+y1) + 0.1*max(y0,y1)), x *= (1+score)
//   NORM: ChannelNorm (unbiased var) + ReLU -> bf16 into haloed y buffer
//   !NORM: write gated fp32 row to d_out
// BF16IN: input rows are bf16 (conv output h), else fp32
// ---------------------------------------------------------------------------
template<bool GATE, bool NORM, bool BF16IN>
__global__ __launch_bounds__(256) void prep_kernel(const void* __restrict__ in_,
                                                   const float* __restrict__ fc,
                                                   const float* __restrict__ cw,
                                                   const float* __restrict__ cb,
                                                   __hip_bfloat16* __restrict__ yout,
                                                   float* __restrict__ fout) {
    const int lane = threadIdx.x & 63;
    const int rid  = blockIdx.x * 4 + (threadIdx.x >> 6);

    int b, t;
    __hip_bfloat16* drow = nullptr;
    if constexpr (NORM) {
        b = rid / SP;
        const int r = rid - b * SP;
        t = r - 8;
        drow = yout + ((size_t)(b * SP + r)) * C_ + lane * 4;
        if (t < 0 || t >= S_) {            // zero halo row
            *(ushort4*)drow = make_ushort4(0, 0, 0, 0);
            return;
        }
    } else {
        b = rid >> 10;
        t = rid & 1023;
    }

    f32x4 xv;
    if constexpr (BF16IN) {
        const __hip_bfloat16* row = (const __hip_bfloat16*)in_ + ((size_t)(b * S_ + t)) * C_;
        bf16x4 hv = *(const bf16x4*)(row + lane * 4);
        xv.x = (float)hv[0]; xv.y = (float)hv[1]; xv.z = (float)hv[2]; xv.w = (float)hv[3];
    } else {
        const float* row = (const float*)in_ + ((size_t)(b * S_ + t)) * C_;
        xv = *(const f32x4*)(row + lane * 4);
    }

    if constexpr (GATE) {
        f32x4 f0 = *(const f32x4*)(fc + lane * 4);
        f32x4 f1 = *(const f32x4*)(fc + C_ + lane * 4);
        float p = xv.x * f0.x + xv.y * f0.y + xv.z * f0.z + xv.w * f0.w;
        float q = xv.x * f1.x + xv.y * f1.y + xv.z * f1.z + xv.w * f1.w;
#pragma unroll
        for (int m = 32; m >= 1; m >>= 1) {
            p += __shfl_xor(p, m, 64);
            q += __shfl_xor(q, m, 64);
        }
        float s = 0.5f * (p + q) + 0.1f * fmaxf(p, q);
        float score = 1.0f / (1.0f + expf(-s));
        float gmul = 1.0f + score;
        xv.x *= gmul; xv.y *= gmul; xv.z *= gmul; xv.w *= gmul;
    }

    if constexpr (NORM) {
        float s1 = xv.x + xv.y + xv.z + xv.w;
        float s2 = xv.x * xv.x + xv.y * xv.y + xv.z * xv.z + xv.w * xv.w;
#pragma unroll
        for (int m = 32; m >= 1; m >>= 1) {
            s1 += __shfl_xor(s1, m, 64);
            s2 += __shfl_xor(s2, m, 64);
        }
        float mean = s1 * (1.0f / 256.0f);
        float var  = fmaxf((s2 - 256.0f * mean * mean) * (1.0f / 255.0f), 0.0f);
        float inv  = rsqrtf(var + 1e-5f);
        f32x4 w4 = *(const f32x4*)(cw + lane * 4);
        f32x4 b4 = *(const f32x4*)(cb + lane * 4);
        float v0 = fmaxf(0.0f, (xv.x - mean) * inv * w4.x + b4.x);
        float v1 = fmaxf(0.0f, (xv.y - mean) * inv * w4.y + b4.y);
        float v2 = fmaxf(0.0f, (xv.z - mean) * inv * w4.z + b4.z);
        float v3 = fmaxf(0.0f, (xv.w - mean) * inv * w4.w + b4.w);
        union { ushort4 u; __hip_bfloat16 e[4]; } o;
        o.e[0] = __float2bfloat16(v0);
        o.e[1] = __float2bfloat16(v1);
        o.e[2] = __float2bfloat16(v2);
        o.e[3] = __float2bfloat16(v3);
        *(ushort4*)drow = o.u;
    } else {
        *(f32x4*)(fout + ((size_t)(b * S_ + t)) * C_ + lane * 4) = xv;
    }
}

// ---------------------------------------------------------------------------
// conv v2: block = 8 waves (512 thr), tile 256co x 64t x 2 batches, grid 256.
// Wave: 64co x 64t x 1 batch, mfma_f32_32x32x16_bf16 (2x2 frags x 2 k-substeps).
// Activations in LDS [72 rows][2 batches][256 ci] bf16, 16B-slot swizzle ^(r&7).
// Weights streamed from repacked global (L2/L1-resident, coalesced), no K-loop
// barriers. Epilogue converts to bf16 and zeroes t >= LVALID.
// ---------------------------------------------------------------------------
template<int KS, int PAD, int LVALID>
__global__ __launch_bounds__(512) void conv_kernel(const __hip_bfloat16* __restrict__ y,
                                                   const __hip_bfloat16* __restrict__ wb,
                                                   __hip_bfloat16* __restrict__ hout) {
    __shared__ alignas(16) __hip_bfloat16 ly[72 * 2 * 256];
    const int tid  = threadIdx.x;
    const int lane = tid & 63;
    const int wv   = tid >> 6;
    const int tt   = blockIdx.x & 15;
    const int bp   = blockIdx.x >> 4;
    const int t0   = tt << 6;
    const int b2   = bp * 2;

    // stage 2 batches x 72 rows x 256 ci (rows t0-PAD .. t0-PAD+71, padded coords)
#pragma unroll
    for (int c = 0; c < 9; ++c) {
        int u = c * 512 + tid;          // 16B unit
        int r = u >> 6, q = u & 63;
        int bbs = q >> 5, s = q & 31;
        const __hip_bfloat16* src = y + ((size_t)((b2 + bbs) * SP + 8 + t0 - PAD + r)) * C_
                                      + ((s ^ (r & 7)) << 3);
        *(bf16x8*)(ly + (size_t)u * 8) = *(const bf16x8*)src;
    }
    __syncthreads();

    const int bb      = wv & 1;
    const int co_base = (wv >> 1) * 64;
    const int l31     = lane & 31;
    const int hh      = lane >> 5;

    f32x16 acc[2][2];
#pragma unroll
    for (int mf = 0; mf < 2; ++mf)
#pragma unroll
        for (int nf = 0; nf < 2; ++nf)
#pragma unroll
            for (int e = 0; e < 16; ++e)
                acc[mf][nf][e] = 0.0f;

    const __hip_bfloat16* abase = wb + (size_t)hh * 2048 + (size_t)(co_base + l31) * 8;
    const __hip_bfloat16* lbb   = ly + bb * 256;

#pragma unroll 4
    for (int s = 0; s < KS * 8; ++s) {
        const int j   = s >> 3;
        const int c32 = s & 7;
        bf16x8 a[2][2], bf[2][2];
#pragma unroll
        for (int ks = 0; ks < 2; ++ks)
#pragma unroll
            for (int mf = 0; mf < 2; ++mf)
                a[ks][mf] = *(const bf16x8*)(abase + (size_t)(s * 4 + ks * 2) * 2048 + mf * 256);
#pragma unroll
        for (int ks = 0; ks < 2; ++ks)
#pragma unroll
            for (int nf = 0; nf < 2; ++nf) {
                int r   = nf * 32 + l31 + j;
                int ci8 = c32 * 4 + ks * 2 + hh;
                bf[ks][nf] = *(const bf16x8*)(lbb + (size_t)r * 512 + ((ci8 ^ (r & 7)) << 3));
            }
#pragma unroll
        for (int ks = 0; ks < 2; ++ks)
#pragma unroll
            for (int mf = 0; mf < 2; ++mf)
#pragma unroll
                for (int nf = 0; nf < 2; ++nf)
                    acc[mf][nf] = __builtin_amdgcn_mfma_f32_32x32x16_bf16(
                        a[ks][mf], bf[ks][nf], acc[mf][nf], 0, 0, 0);
    }

    // epilogue: D col = lane&31 -> t, row = (reg&3) + 8*(reg>>2) + 4*(lane>>5) -> co
    __hip_bfloat16* hb = hout + ((size_t)((b2 + bb) * S_ + t0)) * C_ + co_base;
#pragma unroll
    for (int nf = 0; nf < 2; ++nf) {
        int tl = nf * 32 + l31;
        bool zout = (LVALID < S_) && (t0 + tl >= LVALID);
#pragma unroll
        for (int mf = 0; mf < 2; ++mf) {
#pragma unroll
            for (int r4 = 0; r4 < 4; ++r4) {
                int co = mf * 32 + r4 * 8 + hh * 4;
                union { ushort4 u; __hip_bfloat16 e[4]; } o;
#pragma unroll
                for (int q = 0; q < 4; ++q) {
                    float v = zout ? 0.0f : acc[mf][nf][r4 * 4 + q];
                    o.e[q] = __float2bfloat16(v);
                }
                *(ushort4*)(hb + (size_t)tl * C_ + co) = o.u;
            }
        }
    }
}

// ---------------------------------------------------------------------------
extern "C" void kernel_launch(void* const* d_in, const int* in_sizes, int n_in,
                              void* d_out, int out_size, void* d_ws, size_t ws_size,
                              hipStream_t stream) {
    const float* inputs = (const float*)d_in[0];
    const float* cw[5] = { (const float*)d_in[1],  (const float*)d_in[4],
                           (const float*)d_in[7],  (const float*)d_in[10],
                           (const float*)d_in[13] };
    const float* cb[5] = { (const float*)d_in[2],  (const float*)d_in[5],
                           (const float*)d_in[8],  (const float*)d_in[11],
                           (const float*)d_in[14] };
    const float* Wf[5] = { (const float*)d_in[3],  (const float*)d_in[6],
                           (const float*)d_in[9],  (const float*)d_in[12],
                           (const float*)d_in[15] };
    const float* fc = (const float*)d_in[16];

    char* ws = (char*)d_ws;
    __hip_bfloat16* y = (__hip_bfloat16*)ws;              // 32*1040*256*2 = 17,039,360 B
    __hip_bfloat16* h = (__hip_bfloat16*)(ws + 17039360); // 32*1024*256*2 = 16,777,216 B
    __hip_bfloat16* wb[5];
    size_t off = 17039360 + 16777216;
    for (int l = 0; l < 5; ++l) {
        wb[l] = (__hip_bfloat16*)(ws + off);
        off += (size_t)(l + 4) * 65536 * 2;
    }
    float* out = (float*)d_out;

    for (int l = 0; l < 5; ++l) {
        int k = l + 4, n = k * 65536;
        wcvt_kernel<<<(n + 255) / 256, 256, 0, stream>>>(Wf[l], wb[l], k, n);
    }

    const int GN = (B_ * SP) / 4;   // 8320 blocks, 4 rows each
    prep_kernel<false, true, false><<<GN, 256, 0, stream>>>(inputs, fc, cw[0], cb[0], y, nullptr);
    conv_kernel<4, 1, 1023><<<256, 512, 0, stream>>>(y, wb[0], h);
    prep_kernel<true, true, true><<<GN, 256, 0, stream>>>(h, fc, cw[1], cb[1], y, nullptr);
    conv_kernel<5, 2, 1024><<<256, 512, 0, stream>>>(y, wb[1], h);
    prep_kernel<true, true, true><<<GN, 256, 0, stream>>>(h, fc, cw[2], cb[2], y, nullptr);
    conv_kernel<6, 2, 1023><<<256, 512, 0, stream>>>(y, wb[2], h);
    prep_kernel<true, true, true><<<GN, 256, 0, stream>>>(h, fc, cw[3], cb[3], y, nullptr);
    conv_kernel<7, 3, 1024><<<256, 512, 0, stream>>>(y, wb[3], h);
    prep_kernel<true, true, true><<<GN, 256, 0, stream>>>(h, fc, cw[4], cb[4], y, nullptr);
    conv_kernel<8, 3, 1023><<<256, 512, 0, stream>>>(y, wb[4], h);
    prep_kernel<true, false, true><<<(B_ * S_) / 4, 256, 0, stream>>>(h, fc, nullptr, nullptr, nullptr, out);
}